// Round 5
// baseline (1615.174 us; speedup 1.0000x reference)
//
#include <hip/hip_runtime.h>
#include <math.h>

// Problem constants
#define BSZ 64
#define NPTS 512
#define DIM 256
#define MROWS 32768      // BSZ*NPTS
#define TOTROWS 65536
#define BIGF 1.0e9f

typedef __bf16 bf16x8 __attribute__((ext_vector_type(8)));
typedef float  f32x4  __attribute__((ext_vector_type(4)));

// ws layout (float offsets)
#define KB_OFF    0ull          // K bf16: ushort[16777216]
#define E_OFF     8388608ull    // Ebf: ushort[16777216]
#define H_OFF     16777216ull   // Hbf: ushort[16777216]
#define NORM_OFF  25165824ull   // 65536 f32
#define U_OFF     25231360ull   // 32768 f32
#define V_OFF     25264128ull   // 32768 f32
#define ARGA_OFF  25296896ull   // 32768 int
#define ARGB_OFF  25329664ull   // 32768 int
#define ACC_OFF   25362432ull   // 512 f32 (321 used)
#define WT1_OFF   25362944ull   // ushort[65536]
#define WT2_OFF   25395712ull   // ushort[65536]

#define ACC_PA   0
#define ACC_IN   1     // 64 slots
#define ACC_SUP  65    // 256 slots
#define ACC_CNT  321

__device__ __forceinline__ float bf2f(unsigned short h) {
    return __uint_as_float(((unsigned int)h) << 16);
}
__device__ __forceinline__ unsigned short f2bf(float f) {
    unsigned int u = __float_as_uint(f);
    u = (u + 0x7FFFu + ((u >> 16) & 1u)) >> 16;
    return (unsigned short)u;
}

// re-entrant
__device__ __forceinline__ float block_reduce_256(float val) {
    __shared__ float sh[4];
    int lane = threadIdx.x & 63;
    int wv = threadIdx.x >> 6;
    __syncthreads();
#pragma unroll
    for (int off = 32; off > 0; off >>= 1) val += __shfl_down(val, off, 64);
    if (lane == 0) sh[wv] = val;
    __syncthreads();
    float r = 0.f;
    if (wv == 0 && lane < 4) r = sh[lane];
    if (wv == 0) {
        r += __shfl_down(r, 2, 64);
        r += __shfl_down(r, 1, 64);
    }
    return r;  // valid in thread 0
}

__global__ void zero_acc_kernel(float* acc) {
    int t = blockIdx.x * 256 + threadIdx.x;
    if (t < ACC_CNT) acc[t] = 0.f;
}

__global__ __launch_bounds__(256) void argmax_pa_kernel(
    const float* __restrict__ la, const float* __restrict__ lb,
    const float* __restrict__ pa, int* __restrict__ argA, int* __restrict__ argB,
    float* __restrict__ acc) {
    int i = blockIdx.x * 256 + threadIdx.x;
    float4 a = *(const float4*)&la[(size_t)i * 4];
    float av[4] = {a.x, a.y, a.z, a.w};
    int ba = 0; float bv = av[0];
#pragma unroll
    for (int c = 1; c < 4; ++c) if (av[c] > bv) { bv = av[c]; ba = c; }
    argA[i] = ba;
    float4 b = *(const float4*)&lb[(size_t)i * 4];
    float bw[4] = {b.x, b.y, b.z, b.w};
    int bbi = 0; float bm = bw[0];
#pragma unroll
    for (int c = 1; c < 4; ++c) if (bw[c] > bm) { bm = bw[c]; bbi = c; }
    argB[i] = bbi;
    float p = pa[i];
#pragma unroll
    for (int off = 32; off > 0; off >>= 1) p += __shfl_down(p, off, 64);
    if ((threadIdx.x & 63) == 0) atomicAdd(&acc[ACC_PA], p);
}

// W[256][256] f32 -> Wt[n][k] bf16 (transposed)
__global__ __launch_bounds__(256) void cast_wt_kernel(
    const float* __restrict__ W, unsigned short* __restrict__ Wt) {
    __shared__ float tile[16][17];
    int tx = threadIdx.x & 15, ty = threadIdx.x >> 4;
    int bx = blockIdx.x, by = blockIdx.y;
    tile[ty][tx] = W[(size_t)(by * 16 + ty) * 256 + bx * 16 + tx];
    __syncthreads();
    Wt[(size_t)(bx * 16 + ty) * 256 + by * 16 + tx] = f2bf(tile[tx][ty]);
}

// Fused: Y(bf16) = LN(leaky(X @ W + bias)) * g + be, optional row sq-norms.
template <bool IN_F32>
__global__ __launch_bounds__(256) void gemm_ln_kernel(
    const void* __restrict__ Xv, const unsigned short* __restrict__ Wt,
    const float* __restrict__ bias, const float* __restrict__ gam,
    const float* __restrict__ bet, unsigned short* __restrict__ Y,
    float* __restrict__ norms) {
    __shared__ unsigned short Xs[64 * 40];
    __shared__ unsigned short Ws[256 * 40];
    const int t = threadIdx.x;
    const int L = t & 63, wv = t >> 6;
    const int q = L >> 4, n = L & 15;
    const size_t row0 = (size_t)blockIdx.x * 64;
    f32x4 acc[16];
#pragma unroll
    for (int nt = 0; nt < 16; ++nt) acc[nt] = (f32x4){0.f, 0.f, 0.f, 0.f};

    for (int k0 = 0; k0 < 256; k0 += 32) {
        {
            int r = t >> 2, seg = t & 3;
            if (IN_F32) {
                const float* Xf = (const float*)Xv;
                float4 aa = *(const float4*)&Xf[(row0 + r) * 256 + k0 + seg * 8];
                float4 bb = *(const float4*)&Xf[(row0 + r) * 256 + k0 + seg * 8 + 4];
                uint4 pk;
                pk.x = (unsigned)f2bf(aa.x) | ((unsigned)f2bf(aa.y) << 16);
                pk.y = (unsigned)f2bf(aa.z) | ((unsigned)f2bf(aa.w) << 16);
                pk.z = (unsigned)f2bf(bb.x) | ((unsigned)f2bf(bb.y) << 16);
                pk.w = (unsigned)f2bf(bb.z) | ((unsigned)f2bf(bb.w) << 16);
                *(uint4*)&Xs[r * 40 + seg * 8] = pk;
            } else {
                const unsigned short* Xh = (const unsigned short*)Xv;
                *(uint4*)&Xs[r * 40 + seg * 8] =
                    *(const uint4*)&Xh[(row0 + r) * 256 + k0 + seg * 8];
            }
#pragma unroll
            for (int it = 0; it < 4; ++it) {
                int nn = (t >> 2) + it * 64;
                *(uint4*)&Ws[nn * 40 + seg * 8] =
                    *(const uint4*)&Wt[(size_t)nn * 256 + k0 + seg * 8];
            }
        }
        __syncthreads();
        bf16x8 av = *(const bf16x8*)&Xs[(wv * 16 + n) * 40 + q * 8];
#pragma unroll
        for (int nt = 0; nt < 16; ++nt) {
            bf16x8 bv = *(const bf16x8*)&Ws[(nt * 16 + n) * 40 + q * 8];
            acc[nt] = __builtin_amdgcn_mfma_f32_16x16x32_bf16(av, bv, acc[nt], 0, 0, 0);
        }
        __syncthreads();
    }
    float s[4] = {0.f, 0.f, 0.f, 0.f}, sq[4] = {0.f, 0.f, 0.f, 0.f};
#pragma unroll
    for (int nt = 0; nt < 16; ++nt) {
        float bv = bias[nt * 16 + n];
#pragma unroll
        for (int r = 0; r < 4; ++r) {
            float h = acc[nt][r] + bv;
            h = h >= 0.f ? h : 0.01f * h;
            acc[nt][r] = h;
            s[r] += h; sq[r] += h * h;
        }
    }
#pragma unroll
    for (int r = 0; r < 4; ++r) {
#pragma unroll
        for (int off = 8; off >= 1; off >>= 1) {
            s[r] += __shfl_xor(s[r], off, 64);
            sq[r] += __shfl_xor(sq[r], off, 64);
        }
    }
    float mean[4], inv[4];
#pragma unroll
    for (int r = 0; r < 4; ++r) {
        mean[r] = s[r] * (1.f / 256.f);
        float var = fmaxf(sq[r] * (1.f / 256.f) - mean[r] * mean[r], 0.f);
        inv[r] = rsqrtf(var + 1e-5f);
    }
    float nr[4] = {0.f, 0.f, 0.f, 0.f};
#pragma unroll
    for (int nt = 0; nt < 16; ++nt) {
        float gv = gam[nt * 16 + n], ev = bet[nt * 16 + n];
#pragma unroll
        for (int r = 0; r < 4; ++r) {
            float o = (acc[nt][r] - mean[r]) * inv[r] * gv + ev;
            unsigned short ob = f2bf(o);
            size_t row = row0 + wv * 16 + q * 4 + r;
            Y[row * 256 + nt * 16 + n] = ob;
            float orr = bf2f(ob);
            nr[r] += orr * orr;
        }
    }
    if (norms) {
#pragma unroll
        for (int r = 0; r < 4; ++r) {
#pragma unroll
            for (int off = 8; off >= 1; off >>= 1) nr[r] += __shfl_xor(nr[r], off, 64);
        }
        if (n == 0) {
#pragma unroll
            for (int r = 0; r < 4; ++r)
                norms[row0 + wv * 16 + q * 4 + r] = nr[r];
        }
    }
}

// cdist via MFMA + in/out loss partial + K(bf16) = exp(-2*cost)
__global__ __launch_bounds__(256) void cost_mfma_kernel(
    const unsigned short* __restrict__ E, const float* __restrict__ norms,
    const int* __restrict__ argA, const int* __restrict__ argB,
    const float* __restrict__ pa, const float* __restrict__ pb,
    unsigned short* __restrict__ Kb16, float* __restrict__ acc) {
    __shared__ unsigned short As[64 * 40];
    __shared__ unsigned short Bs[64 * 40];
    const int t = threadIdx.x;
    const int L = t & 63, wv = t >> 6;
    const int q = L >> 4, n = L & 15;
    const int b = blockIdx.z;
    const int i0 = blockIdx.y * 64, j0 = blockIdx.x * 64;
    const unsigned short* eA = E + (size_t)b * 512 * 256;
    const unsigned short* eB = E + (size_t)(32768 + b * 512) * 256;
    f32x4 dot[4];
#pragma unroll
    for (int nt = 0; nt < 4; ++nt) dot[nt] = (f32x4){0.f, 0.f, 0.f, 0.f};

    for (int k0 = 0; k0 < 256; k0 += 32) {
        int r = t >> 2, seg = t & 3;
        *(uint4*)&As[r * 40 + seg * 8] =
            *(const uint4*)&eA[(size_t)(i0 + r) * 256 + k0 + seg * 8];
        *(uint4*)&Bs[r * 40 + seg * 8] =
            *(const uint4*)&eB[(size_t)(j0 + r) * 256 + k0 + seg * 8];
        __syncthreads();
        bf16x8 av = *(const bf16x8*)&As[(wv * 16 + n) * 40 + q * 8];
#pragma unroll
        for (int nt = 0; nt < 4; ++nt) {
            bf16x8 bv = *(const bf16x8*)&Bs[(nt * 16 + n) * 40 + q * 8];
            dot[nt] = __builtin_amdgcn_mfma_f32_16x16x32_bf16(av, bv, dot[nt], 0, 0, 0);
        }
        __syncthreads();
    }
    int base_row = i0 + wv * 16 + q * 4;
    float nA[4], pA[4]; int cA[4];
#pragma unroll
    for (int r = 0; r < 4; ++r) {
        nA[r] = norms[b * 512 + base_row + r];
        pA[r] = pa[b * 512 + base_row + r];
        cA[r] = argA[b * 512 + base_row + r];
    }
    float part = 0.f;
#pragma unroll
    for (int nt = 0; nt < 4; ++nt) {
        int col = j0 + nt * 16 + n;
        float nB = norms[32768 + b * 512 + col];
        float pB = pb[b * 512 + col];
        int cB = argB[b * 512 + col];
#pragma unroll
        for (int r = 0; r < 4; ++r) {
            float d2 = nA[r] + nB - 2.f * dot[nt][r];
            float c = sqrtf(fmaxf(d2, 0.f));
            float pm = pA[r] * pB;
            float cc = c + (BIGF - BIGF * pm);
            float sgn = (cA[r] == cB) ? 1.f : -1.f;
            part += cc * sgn * pm;
            Kb16[((size_t)b * 512 + base_row + r) * 512 + col] = f2bf(expf(-2.f * cc));
        }
    }
    float tot = block_reduce_256(part);
    if (threadIdx.x == 0) atomicAdd(&acc[ACC_IN + b], tot);
}

// In-register persistent Sinkhorn: 1 block (512 thr, 8 waves) per batch.
// Thread (rg = t>>4, cg = t&15) owns rows rg*16..+15, cols cg*32..+31.
// K cols 0..19 of the tile live in 160 VGPRs (packed bf16x2); cols 20..31
// re-read from L2 each pass. Row sums reduce in-wave (shfl_xor over cg);
// col sums via 2-stage LDS reduction (swizzled, conflict-free).
__global__ __launch_bounds__(512) void sinkhorn_reg_kernel(
    const unsigned short* __restrict__ Kb16, float* __restrict__ u,
    float* __restrict__ v) {
    __shared__ float scratch[8 * 528];   // [wave][cg*33 + c] col partials
    __shared__ float vfinal[16 * 33];    // [cg*33 + c]
    const int b = blockIdx.x;
    const int t = threadIdx.x;
    const int cg = t & 15, rg = t >> 4;
    const int wv = t >> 6;
    const float inv512 = 1.f / 512.f;
    const unsigned short* Kbase =
        Kb16 + (size_t)b * 262144 + (size_t)(rg * 16) * 512 + cg * 32;

    // load reg-resident part: cols 0..19 (uints 0..9 per row)
    unsigned int kreg[160];
#pragma unroll
    for (int r = 0; r < 16; ++r) {
        const unsigned short* rp = Kbase + (size_t)r * 512;
        uint4 q0 = *(const uint4*)(rp);
        uint4 q1 = *(const uint4*)(rp + 8);
        uint2 d2 = *(const uint2*)(rp + 16);
        kreg[r * 10 + 0] = q0.x; kreg[r * 10 + 1] = q0.y;
        kreg[r * 10 + 2] = q0.z; kreg[r * 10 + 3] = q0.w;
        kreg[r * 10 + 4] = q1.x; kreg[r * 10 + 5] = q1.y;
        kreg[r * 10 + 6] = q1.z; kreg[r * 10 + 7] = q1.w;
        kreg[r * 10 + 8] = d2.x; kreg[r * 10 + 9] = d2.y;
    }
    float u_reg[16];
#pragma unroll
    for (int r = 0; r < 16; ++r) u_reg[r] = inv512;
    float ca[32];

    for (int it = 0; it < 10; ++it) {
        // ---- v-step: col partial sums over own 16 rows
#pragma unroll
        for (int c = 0; c < 32; ++c) ca[c] = 0.f;
#pragma unroll
        for (int r = 0; r < 16; ++r) {
            float ur = u_reg[r];
#pragma unroll
            for (int m = 0; m < 10; ++m) {
                unsigned int w = kreg[r * 10 + m];
                ca[2 * m]     = fmaf(__uint_as_float(w << 16), ur, ca[2 * m]);
                ca[2 * m + 1] = fmaf(__uint_as_float(w & 0xFFFF0000u), ur, ca[2 * m + 1]);
            }
            const unsigned short* rp = Kbase + (size_t)r * 512;
            uint2 gd = *(const uint2*)(rp + 20);
            uint4 gq = *(const uint4*)(rp + 24);
            ca[20] = fmaf(__uint_as_float(gd.x << 16), ur, ca[20]);
            ca[21] = fmaf(__uint_as_float(gd.x & 0xFFFF0000u), ur, ca[21]);
            ca[22] = fmaf(__uint_as_float(gd.y << 16), ur, ca[22]);
            ca[23] = fmaf(__uint_as_float(gd.y & 0xFFFF0000u), ur, ca[23]);
            ca[24] = fmaf(__uint_as_float(gq.x << 16), ur, ca[24]);
            ca[25] = fmaf(__uint_as_float(gq.x & 0xFFFF0000u), ur, ca[25]);
            ca[26] = fmaf(__uint_as_float(gq.y << 16), ur, ca[26]);
            ca[27] = fmaf(__uint_as_float(gq.y & 0xFFFF0000u), ur, ca[27]);
            ca[28] = fmaf(__uint_as_float(gq.z << 16), ur, ca[28]);
            ca[29] = fmaf(__uint_as_float(gq.z & 0xFFFF0000u), ur, ca[29]);
            ca[30] = fmaf(__uint_as_float(gq.w << 16), ur, ca[30]);
            ca[31] = fmaf(__uint_as_float(gq.w & 0xFFFF0000u), ur, ca[31]);
        }
        // reduce over the 4 rgs within each wave (lanes l^16, l^32 share cg)
#pragma unroll
        for (int c = 0; c < 32; ++c) {
            ca[c] += __shfl_xor(ca[c], 16, 64);
            ca[c] += __shfl_xor(ca[c], 32, 64);
        }
        if ((t & 48) == 0) {
#pragma unroll
            for (int c = 0; c < 32; ++c) scratch[wv * 528 + cg * 33 + c] = ca[c];
        }
        __syncthreads();
        // stage 2: thread g (=t) sums 8 wave-partials for global col g
        {
            int g = t;
            int sidx = (g >> 5) * 33 + (g & 31);
            float ssum = 0.f;
#pragma unroll
            for (int w = 0; w < 8; ++w) ssum += scratch[w * 528 + sidx];
            vfinal[sidx] = inv512 / ssum;
        }
        __syncthreads();
        // gather v for own 32 cols (broadcast across rg; conflict-free stride 33)
#pragma unroll
        for (int c = 0; c < 32; ++c) ca[c] = vfinal[cg * 33 + c];
        __syncthreads();   // vfinal/scratch reusable next iter
        // ---- u-step: row sums, fully in-wave reduction over cg (xor 1,2,4,8)
#pragma unroll
        for (int r = 0; r < 16; ++r) {
            float s = 0.f;
#pragma unroll
            for (int m = 0; m < 10; ++m) {
                unsigned int w = kreg[r * 10 + m];
                s = fmaf(__uint_as_float(w << 16), ca[2 * m], s);
                s = fmaf(__uint_as_float(w & 0xFFFF0000u), ca[2 * m + 1], s);
            }
            const unsigned short* rp = Kbase + (size_t)r * 512;
            uint2 gd = *(const uint2*)(rp + 20);
            uint4 gq = *(const uint4*)(rp + 24);
            s = fmaf(__uint_as_float(gd.x << 16), ca[20], s);
            s = fmaf(__uint_as_float(gd.x & 0xFFFF0000u), ca[21], s);
            s = fmaf(__uint_as_float(gd.y << 16), ca[22], s);
            s = fmaf(__uint_as_float(gd.y & 0xFFFF0000u), ca[23], s);
            s = fmaf(__uint_as_float(gq.x << 16), ca[24], s);
            s = fmaf(__uint_as_float(gq.x & 0xFFFF0000u), ca[25], s);
            s = fmaf(__uint_as_float(gq.y << 16), ca[26], s);
            s = fmaf(__uint_as_float(gq.y & 0xFFFF0000u), ca[27], s);
            s = fmaf(__uint_as_float(gq.z << 16), ca[28], s);
            s = fmaf(__uint_as_float(gq.z & 0xFFFF0000u), ca[29], s);
            s = fmaf(__uint_as_float(gq.w << 16), ca[30], s);
            s = fmaf(__uint_as_float(gq.w & 0xFFFF0000u), ca[31], s);
            s += __shfl_xor(s, 1, 64);
            s += __shfl_xor(s, 2, 64);
            s += __shfl_xor(s, 4, 64);
            s += __shfl_xor(s, 8, 64);
            u_reg[r] = inv512 / s;
        }
    }
    // write out (cg==0 lanes hold u; rg==0 threads hold v for their cols)
    if (cg == 0) {
#pragma unroll
        for (int r = 0; r < 16; ++r) u[(size_t)b * 512 + rg * 16 + r] = u_reg[r];
    }
    if (rg == 0) {
#pragma unroll
        for (int c = 0; c < 32; ++c) v[(size_t)b * 512 + cg * 32 + c] = ca[c];
    }
}

// sup loss on bf16 K
__global__ __launch_bounds__(256) void sup_kernel(
    const unsigned short* __restrict__ Kb16, const float* __restrict__ u,
    const float* __restrict__ v, const float* __restrict__ rel,
    const float* __restrict__ pa, float* __restrict__ acc) {
    const int nthreads = 4096 * 256;
    int tid = blockIdx.x * 256 + threadIdx.x;
    float part = 0.f;
#pragma unroll
    for (int k = 0; k < 4; ++k) {
        int i4 = tid + k * nthreads;
        int e = i4 * 4;
        int b = e >> 18;
        int i = (e >> 9) & 511;
        int j0 = e & 511;
        ushort4 K4 = *(const ushort4*)&Kb16[(size_t)i4 * 4];
        float4 r4 = *(const float4*)&rel[(size_t)i4 * 4];
        float4 v4 = *(const float4*)&v[b * 512 + j0];
        float ui = u[b * 512 + i] * 512.f;
        float pai = pa[b * 512 + i];
        float d0 = ui * bf2f(K4.x) * v4.x - r4.x;
        float d1 = ui * bf2f(K4.y) * v4.y - r4.y;
        float d2 = ui * bf2f(K4.z) * v4.z - r4.z;
        float d3 = ui * bf2f(K4.w) * v4.w - r4.w;
        part += (d0 * d0 + d1 * d1 + d2 * d2 + d3 * d3) * pai;
    }
    float tot = block_reduce_256(part);
    if (threadIdx.x == 0) atomicAdd(&acc[ACC_SUP + (blockIdx.x & 255)], tot);
}

__global__ __launch_bounds__(256) void final_kernel(const float* __restrict__ acc,
                                                    float* __restrict__ out) {
    int t = threadIdx.x;
    float vin = (t < 64) ? acc[ACC_IN + t] : 0.f;
    float sIn = block_reduce_256(vin);
    float vsup = acc[ACC_SUP + t];
    float sSup = block_reduce_256(vsup);
    if (t == 0)
        out[0] = sIn * (1.f / 16777216.f) + 10.f * sSup / acc[ACC_PA];
}

extern "C" void kernel_launch(void* const* d_in, const int* in_sizes, int n_in,
                              void* d_out, int out_size, void* d_ws, size_t ws_size,
                              hipStream_t stream) {
    const float* la  = (const float*)d_in[0];
    const float* lb  = (const float*)d_in[1];
    const float* xA  = (const float*)d_in[2];
    const float* xB  = (const float*)d_in[3];
    const float* rel = (const float*)d_in[4];
    const float* pa  = (const float*)d_in[5];
    const float* pb  = (const float*)d_in[6];
    const float* W1  = (const float*)d_in[7];
    const float* b1  = (const float*)d_in[8];
    const float* g1  = (const float*)d_in[9];
    const float* be1 = (const float*)d_in[10];
    const float* W2  = (const float*)d_in[11];
    const float* b2  = (const float*)d_in[12];
    const float* g2  = (const float*)d_in[13];
    const float* be2 = (const float*)d_in[14];
    float* out = (float*)d_out;

    float* ws = (float*)d_ws;
    unsigned short* Kb16 = (unsigned short*)(ws + KB_OFF);
    unsigned short* Ebf  = (unsigned short*)(ws + E_OFF);
    unsigned short* Hbf  = (unsigned short*)(ws + H_OFF);
    float* norms = ws + NORM_OFF;
    float* u     = ws + U_OFF;
    float* v     = ws + V_OFF;
    int* argA    = (int*)(ws + ARGA_OFF);
    int* argB    = (int*)(ws + ARGB_OFF);
    float* acc   = ws + ACC_OFF;
    unsigned short* Wt1 = (unsigned short*)(ws + WT1_OFF);
    unsigned short* Wt2 = (unsigned short*)(ws + WT2_OFF);

    zero_acc_kernel<<<2, 256, 0, stream>>>(acc);
    argmax_pa_kernel<<<128, 256, 0, stream>>>(la, lb, pa, argA, argB, acc);

    cast_wt_kernel<<<dim3(16, 16), 256, 0, stream>>>(W1, Wt1);
    cast_wt_kernel<<<dim3(16, 16), 256, 0, stream>>>(W2, Wt2);

    // layer 1 (fused cast+gemm+bias+leaky+LN): f32 in, bf16 out
    gemm_ln_kernel<true><<<512, 256, 0, stream>>>(xA, Wt1, b1, g1, be1, Hbf, nullptr);
    gemm_ln_kernel<true><<<512, 256, 0, stream>>>(xB, Wt1, b1, g1, be1,
                                                  Hbf + (size_t)MROWS * DIM, nullptr);
    // layer 2: bf16 in, bf16 out + row norms
    gemm_ln_kernel<false><<<1024, 256, 0, stream>>>(Hbf, Wt2, b2, g2, be2, Ebf, norms);

    // cost + K(bf16)
    cost_mfma_kernel<<<dim3(8, 8, 64), 256, 0, stream>>>(Ebf, norms, argA, argB, pa, pb,
                                                         Kb16, acc);

    // sinkhorn: in-register persistent, 1 block/batch
    sinkhorn_reg_kernel<<<64, 512, 0, stream>>>(Kb16, u, v);

    sup_kernel<<<4096, 256, 0, stream>>>(Kb16, u, v, rel, pa, acc);
    final_kernel<<<1, 256, 0, stream>>>(acc, out);
}

// Round 6
// 1584.617 us; speedup vs baseline: 1.0193x; 1.0193x over previous
//
#include <hip/hip_runtime.h>
#include <math.h>

// Problem constants
#define BSZ 64
#define NPTS 512
#define DIM 256
#define MROWS 32768      // BSZ*NPTS
#define TOTROWS 65536
#define BIGF 1.0e9f

typedef __bf16 bf16x8 __attribute__((ext_vector_type(8)));
typedef float  f32x4  __attribute__((ext_vector_type(4)));

// ws layout (float offsets)
#define KB_OFF    0ull          // K bf16: ushort[16777216]
#define E_OFF     8388608ull    // Ebf: ushort[16777216]
#define H_OFF     16777216ull   // Hbf: ushort[16777216]
#define NORM_OFF  25165824ull   // 65536 f32
#define U_OFF     25231360ull   // 32768 f32
#define V_OFF     25264128ull   // 32768 f32
#define ARGA_OFF  25296896ull   // 32768 int
#define ARGB_OFF  25329664ull   // 32768 int
#define ACC_OFF   25362432ull   // 512 f32 (321 used)
#define WT1_OFF   25362944ull   // ushort[65536]
#define WT2_OFF   25395712ull   // ushort[65536]

#define ACC_PA   0
#define ACC_IN   1     // 64 slots
#define ACC_SUP  65    // 256 slots
#define ACC_CNT  321

__device__ __forceinline__ float bf2f(unsigned short h) {
    return __uint_as_float(((unsigned int)h) << 16);
}
__device__ __forceinline__ unsigned short f2bf(float f) {
    unsigned int u = __float_as_uint(f);
    u = (u + 0x7FFFu + ((u >> 16) & 1u)) >> 16;
    return (unsigned short)u;
}

// re-entrant
__device__ __forceinline__ float block_reduce_256(float val) {
    __shared__ float sh[4];
    int lane = threadIdx.x & 63;
    int wv = threadIdx.x >> 6;
    __syncthreads();
#pragma unroll
    for (int off = 32; off > 0; off >>= 1) val += __shfl_down(val, off, 64);
    if (lane == 0) sh[wv] = val;
    __syncthreads();
    float r = 0.f;
    if (wv == 0 && lane < 4) r = sh[lane];
    if (wv == 0) {
        r += __shfl_down(r, 2, 64);
        r += __shfl_down(r, 1, 64);
    }
    return r;  // valid in thread 0
}

__global__ void zero_acc_kernel(float* acc) {
    int t = blockIdx.x * 256 + threadIdx.x;
    if (t < ACC_CNT) acc[t] = 0.f;
}

__global__ __launch_bounds__(256) void argmax_pa_kernel(
    const float* __restrict__ la, const float* __restrict__ lb,
    const float* __restrict__ pa, int* __restrict__ argA, int* __restrict__ argB,
    float* __restrict__ acc) {
    int i = blockIdx.x * 256 + threadIdx.x;
    float4 a = *(const float4*)&la[(size_t)i * 4];
    float av[4] = {a.x, a.y, a.z, a.w};
    int ba = 0; float bv = av[0];
#pragma unroll
    for (int c = 1; c < 4; ++c) if (av[c] > bv) { bv = av[c]; ba = c; }
    argA[i] = ba;
    float4 b = *(const float4*)&lb[(size_t)i * 4];
    float bw[4] = {b.x, b.y, b.z, b.w};
    int bbi = 0; float bm = bw[0];
#pragma unroll
    for (int c = 1; c < 4; ++c) if (bw[c] > bm) { bm = bw[c]; bbi = c; }
    argB[i] = bbi;
    float p = pa[i];
#pragma unroll
    for (int off = 32; off > 0; off >>= 1) p += __shfl_down(p, off, 64);
    if ((threadIdx.x & 63) == 0) atomicAdd(&acc[ACC_PA], p);
}

// W[256][256] f32 -> Wt[n][k] bf16 (transposed)
__global__ __launch_bounds__(256) void cast_wt_kernel(
    const float* __restrict__ W, unsigned short* __restrict__ Wt) {
    __shared__ float tile[16][17];
    int tx = threadIdx.x & 15, ty = threadIdx.x >> 4;
    int bx = blockIdx.x, by = blockIdx.y;
    tile[ty][tx] = W[(size_t)(by * 16 + ty) * 256 + bx * 16 + tx];
    __syncthreads();
    Wt[(size_t)(bx * 16 + ty) * 256 + by * 16 + tx] = f2bf(tile[tx][ty]);
}

// Fused: Y(bf16) = LN(leaky(X @ W + bias)) * g + be, optional row sq-norms.
template <bool IN_F32>
__global__ __launch_bounds__(256) void gemm_ln_kernel(
    const void* __restrict__ Xv, const unsigned short* __restrict__ Wt,
    const float* __restrict__ bias, const float* __restrict__ gam,
    const float* __restrict__ bet, unsigned short* __restrict__ Y,
    float* __restrict__ norms) {
    __shared__ unsigned short Xs[64 * 40];
    __shared__ unsigned short Ws[256 * 40];
    const int t = threadIdx.x;
    const int L = t & 63, wv = t >> 6;
    const int q = L >> 4, n = L & 15;
    const size_t row0 = (size_t)blockIdx.x * 64;
    f32x4 acc[16];
#pragma unroll
    for (int nt = 0; nt < 16; ++nt) acc[nt] = (f32x4){0.f, 0.f, 0.f, 0.f};

    for (int k0 = 0; k0 < 256; k0 += 32) {
        {
            int r = t >> 2, seg = t & 3;
            if (IN_F32) {
                const float* Xf = (const float*)Xv;
                float4 aa = *(const float4*)&Xf[(row0 + r) * 256 + k0 + seg * 8];
                float4 bb = *(const float4*)&Xf[(row0 + r) * 256 + k0 + seg * 8 + 4];
                uint4 pk;
                pk.x = (unsigned)f2bf(aa.x) | ((unsigned)f2bf(aa.y) << 16);
                pk.y = (unsigned)f2bf(aa.z) | ((unsigned)f2bf(aa.w) << 16);
                pk.z = (unsigned)f2bf(bb.x) | ((unsigned)f2bf(bb.y) << 16);
                pk.w = (unsigned)f2bf(bb.z) | ((unsigned)f2bf(bb.w) << 16);
                *(uint4*)&Xs[r * 40 + seg * 8] = pk;
            } else {
                const unsigned short* Xh = (const unsigned short*)Xv;
                *(uint4*)&Xs[r * 40 + seg * 8] =
                    *(const uint4*)&Xh[(row0 + r) * 256 + k0 + seg * 8];
            }
#pragma unroll
            for (int it = 0; it < 4; ++it) {
                int nn = (t >> 2) + it * 64;
                *(uint4*)&Ws[nn * 40 + seg * 8] =
                    *(const uint4*)&Wt[(size_t)nn * 256 + k0 + seg * 8];
            }
        }
        __syncthreads();
        bf16x8 av = *(const bf16x8*)&Xs[(wv * 16 + n) * 40 + q * 8];
#pragma unroll
        for (int nt = 0; nt < 16; ++nt) {
            bf16x8 bv = *(const bf16x8*)&Ws[(nt * 16 + n) * 40 + q * 8];
            acc[nt] = __builtin_amdgcn_mfma_f32_16x16x32_bf16(av, bv, acc[nt], 0, 0, 0);
        }
        __syncthreads();
    }
    float s[4] = {0.f, 0.f, 0.f, 0.f}, sq[4] = {0.f, 0.f, 0.f, 0.f};
#pragma unroll
    for (int nt = 0; nt < 16; ++nt) {
        float bv = bias[nt * 16 + n];
#pragma unroll
        for (int r = 0; r < 4; ++r) {
            float h = acc[nt][r] + bv;
            h = h >= 0.f ? h : 0.01f * h;
            acc[nt][r] = h;
            s[r] += h; sq[r] += h * h;
        }
    }
#pragma unroll
    for (int r = 0; r < 4; ++r) {
#pragma unroll
        for (int off = 8; off >= 1; off >>= 1) {
            s[r] += __shfl_xor(s[r], off, 64);
            sq[r] += __shfl_xor(sq[r], off, 64);
        }
    }
    float mean[4], inv[4];
#pragma unroll
    for (int r = 0; r < 4; ++r) {
        mean[r] = s[r] * (1.f / 256.f);
        float var = fmaxf(sq[r] * (1.f / 256.f) - mean[r] * mean[r], 0.f);
        inv[r] = rsqrtf(var + 1e-5f);
    }
    float nr[4] = {0.f, 0.f, 0.f, 0.f};
#pragma unroll
    for (int nt = 0; nt < 16; ++nt) {
        float gv = gam[nt * 16 + n], ev = bet[nt * 16 + n];
#pragma unroll
        for (int r = 0; r < 4; ++r) {
            float o = (acc[nt][r] - mean[r]) * inv[r] * gv + ev;
            unsigned short ob = f2bf(o);
            size_t row = row0 + wv * 16 + q * 4 + r;
            Y[row * 256 + nt * 16 + n] = ob;
            float orr = bf2f(ob);
            nr[r] += orr * orr;
        }
    }
    if (norms) {
#pragma unroll
        for (int r = 0; r < 4; ++r) {
#pragma unroll
            for (int off = 8; off >= 1; off >>= 1) nr[r] += __shfl_xor(nr[r], off, 64);
        }
        if (n == 0) {
#pragma unroll
            for (int r = 0; r < 4; ++r)
                norms[row0 + wv * 16 + q * 4 + r] = nr[r];
        }
    }
}

// cdist via MFMA + in/out loss partial + K(bf16) = exp(-2*cost)
__global__ __launch_bounds__(256) void cost_mfma_kernel(
    const unsigned short* __restrict__ E, const float* __restrict__ norms,
    const int* __restrict__ argA, const int* __restrict__ argB,
    const float* __restrict__ pa, const float* __restrict__ pb,
    unsigned short* __restrict__ Kb16, float* __restrict__ acc) {
    __shared__ unsigned short As[64 * 40];
    __shared__ unsigned short Bs[64 * 40];
    const int t = threadIdx.x;
    const int L = t & 63, wv = t >> 6;
    const int q = L >> 4, n = L & 15;
    const int b = blockIdx.z;
    const int i0 = blockIdx.y * 64, j0 = blockIdx.x * 64;
    const unsigned short* eA = E + (size_t)b * 512 * 256;
    const unsigned short* eB = E + (size_t)(32768 + b * 512) * 256;
    f32x4 dot[4];
#pragma unroll
    for (int nt = 0; nt < 4; ++nt) dot[nt] = (f32x4){0.f, 0.f, 0.f, 0.f};

    for (int k0 = 0; k0 < 256; k0 += 32) {
        int r = t >> 2, seg = t & 3;
        *(uint4*)&As[r * 40 + seg * 8] =
            *(const uint4*)&eA[(size_t)(i0 + r) * 256 + k0 + seg * 8];
        *(uint4*)&Bs[r * 40 + seg * 8] =
            *(const uint4*)&eB[(size_t)(j0 + r) * 256 + k0 + seg * 8];
        __syncthreads();
        bf16x8 av = *(const bf16x8*)&As[(wv * 16 + n) * 40 + q * 8];
#pragma unroll
        for (int nt = 0; nt < 4; ++nt) {
            bf16x8 bv = *(const bf16x8*)&Bs[(nt * 16 + n) * 40 + q * 8];
            dot[nt] = __builtin_amdgcn_mfma_f32_16x16x32_bf16(av, bv, dot[nt], 0, 0, 0);
        }
        __syncthreads();
    }
    int base_row = i0 + wv * 16 + q * 4;
    float nA[4], pA[4]; int cA[4];
#pragma unroll
    for (int r = 0; r < 4; ++r) {
        nA[r] = norms[b * 512 + base_row + r];
        pA[r] = pa[b * 512 + base_row + r];
        cA[r] = argA[b * 512 + base_row + r];
    }
    float part = 0.f;
#pragma unroll
    for (int nt = 0; nt < 4; ++nt) {
        int col = j0 + nt * 16 + n;
        float nB = norms[32768 + b * 512 + col];
        float pB = pb[b * 512 + col];
        int cB = argB[b * 512 + col];
#pragma unroll
        for (int r = 0; r < 4; ++r) {
            float d2 = nA[r] + nB - 2.f * dot[nt][r];
            float c = sqrtf(fmaxf(d2, 0.f));
            float pm = pA[r] * pB;
            float cc = c + (BIGF - BIGF * pm);
            float sgn = (cA[r] == cB) ? 1.f : -1.f;
            part += cc * sgn * pm;
            Kb16[((size_t)b * 512 + base_row + r) * 512 + col] = f2bf(expf(-2.f * cc));
        }
    }
    float tot = block_reduce_256(part);
    if (threadIdx.x == 0) atomicAdd(&acc[ACC_IN + b], tot);
}

// In-register persistent Sinkhorn: 1 block (512 thr, 8 waves) per batch.
// Thread (rg = t>>4, cg = t&15) owns rows rg*16..+15, cols cg*32..+31.
// Cols 0..15 of the tile live in 128 VGPRs (packed bf16x2); cols 16..31
// stream from L2 each pass. __launch_bounds__(512, 2): 8 waves = exactly
// 2 waves/EU -> VGPR cap 256 (R5's default target was 128 -> kreg spilled
// to scratch: 589 MB FETCH. This is the fix.)
__global__ __launch_bounds__(512, 2) void sinkhorn_reg_kernel(
    const unsigned short* __restrict__ Kb16, float* __restrict__ u,
    float* __restrict__ v) {
    __shared__ float scratch[8 * 528];   // [wave][cg*33 + c] col partials
    __shared__ float vfinal[16 * 33];    // [cg*33 + c]
    const int b = blockIdx.x;
    const int t = threadIdx.x;
    const int cg = t & 15, rg = t >> 4;
    const int wv = t >> 6;
    const float inv512 = 1.f / 512.f;
    const unsigned short* Kbase =
        Kb16 + (size_t)b * 262144 + (size_t)(rg * 16) * 512 + cg * 32;

    // reg-resident: cols 0..15 (uints 0..7 per row) = kreg[128]
    unsigned int kreg[128];
#pragma unroll
    for (int r = 0; r < 16; ++r) {
        const unsigned short* rp = Kbase + (size_t)r * 512;
        uint4 q0 = *(const uint4*)(rp);
        uint4 q1 = *(const uint4*)(rp + 8);
        kreg[r * 8 + 0] = q0.x; kreg[r * 8 + 1] = q0.y;
        kreg[r * 8 + 2] = q0.z; kreg[r * 8 + 3] = q0.w;
        kreg[r * 8 + 4] = q1.x; kreg[r * 8 + 5] = q1.y;
        kreg[r * 8 + 6] = q1.z; kreg[r * 8 + 7] = q1.w;
    }
    float u_reg[16];
#pragma unroll
    for (int r = 0; r < 16; ++r) u_reg[r] = inv512;
    float ca[32];

    for (int it = 0; it < 10; ++it) {
        // ---- v-step: col partial sums over own 16 rows
#pragma unroll
        for (int c = 0; c < 32; ++c) ca[c] = 0.f;
#pragma unroll
        for (int r = 0; r < 16; ++r) {
            float ur = u_reg[r];
#pragma unroll
            for (int m = 0; m < 8; ++m) {
                unsigned int w = kreg[r * 8 + m];
                ca[2 * m]     = fmaf(__uint_as_float(w << 16), ur, ca[2 * m]);
                ca[2 * m + 1] = fmaf(__uint_as_float(w & 0xFFFF0000u), ur, ca[2 * m + 1]);
            }
            const unsigned short* rp = Kbase + (size_t)r * 512;
            uint4 q2 = *(const uint4*)(rp + 16);
            uint4 q3 = *(const uint4*)(rp + 24);
            unsigned int g[8] = {q2.x, q2.y, q2.z, q2.w, q3.x, q3.y, q3.z, q3.w};
#pragma unroll
            for (int m = 0; m < 8; ++m) {
                unsigned int w = g[m];
                ca[16 + 2 * m]     = fmaf(__uint_as_float(w << 16), ur, ca[16 + 2 * m]);
                ca[17 + 2 * m]     = fmaf(__uint_as_float(w & 0xFFFF0000u), ur, ca[17 + 2 * m]);
            }
        }
        // reduce over the 4 rgs within each wave (lanes l^16, l^32 share cg)
#pragma unroll
        for (int c = 0; c < 32; ++c) {
            ca[c] += __shfl_xor(ca[c], 16, 64);
            ca[c] += __shfl_xor(ca[c], 32, 64);
        }
        if ((t & 48) == 0) {
#pragma unroll
            for (int c = 0; c < 32; ++c) scratch[wv * 528 + cg * 33 + c] = ca[c];
        }
        __syncthreads();
        // stage 2: thread g (=t) sums 8 wave-partials for global col g
        {
            int g = t;
            int sidx = (g >> 5) * 33 + (g & 31);
            float ssum = 0.f;
#pragma unroll
            for (int w = 0; w < 8; ++w) ssum += scratch[w * 528 + sidx];
            vfinal[sidx] = inv512 / ssum;
        }
        __syncthreads();
        // gather v for own 32 cols (broadcast across rg; conflict-free stride 33)
#pragma unroll
        for (int c = 0; c < 32; ++c) ca[c] = vfinal[cg * 33 + c];
        __syncthreads();   // vfinal/scratch reusable next iter
        // ---- u-step: row sums, fully in-wave reduction over cg (xor 1,2,4,8)
#pragma unroll
        for (int r = 0; r < 16; ++r) {
            float s = 0.f;
#pragma unroll
            for (int m = 0; m < 8; ++m) {
                unsigned int w = kreg[r * 8 + m];
                s = fmaf(__uint_as_float(w << 16), ca[2 * m], s);
                s = fmaf(__uint_as_float(w & 0xFFFF0000u), ca[2 * m + 1], s);
            }
            const unsigned short* rp = Kbase + (size_t)r * 512;
            uint4 q2 = *(const uint4*)(rp + 16);
            uint4 q3 = *(const uint4*)(rp + 24);
            unsigned int g[8] = {q2.x, q2.y, q2.z, q2.w, q3.x, q3.y, q3.z, q3.w};
#pragma unroll
            for (int m = 0; m < 8; ++m) {
                unsigned int w = g[m];
                s = fmaf(__uint_as_float(w << 16), ca[16 + 2 * m], s);
                s = fmaf(__uint_as_float(w & 0xFFFF0000u), ca[17 + 2 * m], s);
            }
            s += __shfl_xor(s, 1, 64);
            s += __shfl_xor(s, 2, 64);
            s += __shfl_xor(s, 4, 64);
            s += __shfl_xor(s, 8, 64);
            u_reg[r] = inv512 / s;
        }
    }
    // write out (cg==0 lanes hold u; rg==0 threads hold v for their cols)
    if (cg == 0) {
#pragma unroll
        for (int r = 0; r < 16; ++r) u[(size_t)b * 512 + rg * 16 + r] = u_reg[r];
    }
    if (rg == 0) {
#pragma unroll
        for (int c = 0; c < 32; ++c) v[(size_t)b * 512 + cg * 32 + c] = ca[c];
    }
}

// sup loss on bf16 K
__global__ __launch_bounds__(256) void sup_kernel(
    const unsigned short* __restrict__ Kb16, const float* __restrict__ u,
    const float* __restrict__ v, const float* __restrict__ rel,
    const float* __restrict__ pa, float* __restrict__ acc) {
    const int nthreads = 4096 * 256;
    int tid = blockIdx.x * 256 + threadIdx.x;
    float part = 0.f;
#pragma unroll
    for (int k = 0; k < 4; ++k) {
        int i4 = tid + k * nthreads;
        int e = i4 * 4;
        int b = e >> 18;
        int i = (e >> 9) & 511;
        int j0 = e & 511;
        ushort4 K4 = *(const ushort4*)&Kb16[(size_t)i4 * 4];
        float4 r4 = *(const float4*)&rel[(size_t)i4 * 4];
        float4 v4 = *(const float4*)&v[b * 512 + j0];
        float ui = u[b * 512 + i] * 512.f;
        float pai = pa[b * 512 + i];
        float d0 = ui * bf2f(K4.x) * v4.x - r4.x;
        float d1 = ui * bf2f(K4.y) * v4.y - r4.y;
        float d2 = ui * bf2f(K4.z) * v4.z - r4.z;
        float d3 = ui * bf2f(K4.w) * v4.w - r4.w;
        part += (d0 * d0 + d1 * d1 + d2 * d2 + d3 * d3) * pai;
    }
    float tot = block_reduce_256(part);
    if (threadIdx.x == 0) atomicAdd(&acc[ACC_SUP + (blockIdx.x & 255)], tot);
}

__global__ __launch_bounds__(256) void final_kernel(const float* __restrict__ acc,
                                                    float* __restrict__ out) {
    int t = threadIdx.x;
    float vin = (t < 64) ? acc[ACC_IN + t] : 0.f;
    float sIn = block_reduce_256(vin);
    float vsup = acc[ACC_SUP + t];
    float sSup = block_reduce_256(vsup);
    if (t == 0)
        out[0] = sIn * (1.f / 16777216.f) + 10.f * sSup / acc[ACC_PA];
}

extern "C" void kernel_launch(void* const* d_in, const int* in_sizes, int n_in,
                              void* d_out, int out_size, void* d_ws, size_t ws_size,
                              hipStream_t stream) {
    const float* la  = (const float*)d_in[0];
    const float* lb  = (const float*)d_in[1];
    const float* xA  = (const float*)d_in[2];
    const float* xB  = (const float*)d_in[3];
    const float* rel = (const float*)d_in[4];
    const float* pa  = (const float*)d_in[5];
    const float* pb  = (const float*)d_in[6];
    const float* W1  = (const float*)d_in[7];
    const float* b1  = (const float*)d_in[8];
    const float* g1  = (const float*)d_in[9];
    const float* be1 = (const float*)d_in[10];
    const float* W2  = (const float*)d_in[11];
    const float* b2  = (const float*)d_in[12];
    const float* g2  = (const float*)d_in[13];
    const float* be2 = (const float*)d_in[14];
    float* out = (float*)d_out;

    float* ws = (float*)d_ws;
    unsigned short* Kb16 = (unsigned short*)(ws + KB_OFF);
    unsigned short* Ebf  = (unsigned short*)(ws + E_OFF);
    unsigned short* Hbf  = (unsigned short*)(ws + H_OFF);
    float* norms = ws + NORM_OFF;
    float* u     = ws + U_OFF;
    float* v     = ws + V_OFF;
    int* argA    = (int*)(ws + ARGA_OFF);
    int* argB    = (int*)(ws + ARGB_OFF);
    float* acc   = ws + ACC_OFF;
    unsigned short* Wt1 = (unsigned short*)(ws + WT1_OFF);
    unsigned short* Wt2 = (unsigned short*)(ws + WT2_OFF);

    zero_acc_kernel<<<2, 256, 0, stream>>>(acc);
    argmax_pa_kernel<<<128, 256, 0, stream>>>(la, lb, pa, argA, argB, acc);

    cast_wt_kernel<<<dim3(16, 16), 256, 0, stream>>>(W1, Wt1);
    cast_wt_kernel<<<dim3(16, 16), 256, 0, stream>>>(W2, Wt2);

    // layer 1 (fused cast+gemm+bias+leaky+LN): f32 in, bf16 out
    gemm_ln_kernel<true><<<512, 256, 0, stream>>>(xA, Wt1, b1, g1, be1, Hbf, nullptr);
    gemm_ln_kernel<true><<<512, 256, 0, stream>>>(xB, Wt1, b1, g1, be1,
                                                  Hbf + (size_t)MROWS * DIM, nullptr);
    // layer 2: bf16 in, bf16 out + row norms
    gemm_ln_kernel<false><<<1024, 256, 0, stream>>>(Hbf, Wt2, b2, g2, be2, Ebf, norms);

    // cost + K(bf16)
    cost_mfma_kernel<<<dim3(8, 8, 64), 256, 0, stream>>>(Ebf, norms, argA, argB, pa, pb,
                                                         Kb16, acc);

    // sinkhorn: in-register persistent, 1 block/batch
    sinkhorn_reg_kernel<<<64, 512, 0, stream>>>(Kb16, u, v);

    sup_kernel<<<4096, 256, 0, stream>>>(Kb16, u, v, rel, pa, acc);
    final_kernel<<<1, 256, 0, stream>>>(acc, out);
}

// Round 7
// 593.646 us; speedup vs baseline: 2.7208x; 2.6693x over previous
//
#include <hip/hip_runtime.h>
#include <math.h>

// Problem constants
#define BSZ 64
#define NPTS 512
#define DIM 256
#define MROWS 32768      // BSZ*NPTS
#define TOTROWS 65536
#define BIGF 1.0e9f

typedef __bf16 bf16x8 __attribute__((ext_vector_type(8)));
typedef float  f32x4  __attribute__((ext_vector_type(4)));

// ws layout (float offsets)
#define KB_OFF    0ull          // K bf16: ushort[16777216]
#define E_OFF     8388608ull    // Ebf: ushort[16777216]
#define H_OFF     16777216ull   // Hbf: ushort[16777216]; reused as KT after layer2
#define NORM_OFF  25165824ull   // 65536 f32
#define U_OFF     25231360ull   // 32768 f32
#define V_OFF     25264128ull   // 32768 f32
#define ARGA_OFF  25296896ull   // 32768 int
#define ARGB_OFF  25329664ull   // 32768 int
#define ACC_OFF   25362432ull   // 512 f32 (321 used)
#define WT1_OFF   25362944ull   // ushort[65536]
#define WT2_OFF   25395712ull   // ushort[65536]

#define ACC_PA   0
#define ACC_IN   1     // 64 slots
#define ACC_SUP  65    // 256 slots
#define ACC_CNT  321

__device__ __forceinline__ float bf2f(unsigned short h) {
    return __uint_as_float(((unsigned int)h) << 16);
}
__device__ __forceinline__ unsigned short f2bf(float f) {
    unsigned int u = __float_as_uint(f);
    u = (u + 0x7FFFu + ((u >> 16) & 1u)) >> 16;
    return (unsigned short)u;
}

// re-entrant
__device__ __forceinline__ float block_reduce_256(float val) {
    __shared__ float sh[4];
    int lane = threadIdx.x & 63;
    int wv = threadIdx.x >> 6;
    __syncthreads();
#pragma unroll
    for (int off = 32; off > 0; off >>= 1) val += __shfl_down(val, off, 64);
    if (lane == 0) sh[wv] = val;
    __syncthreads();
    float r = 0.f;
    if (wv == 0 && lane < 4) r = sh[lane];
    if (wv == 0) {
        r += __shfl_down(r, 2, 64);
        r += __shfl_down(r, 1, 64);
    }
    return r;  // valid in thread 0
}

__global__ void zero_acc_kernel(float* acc) {
    int t = blockIdx.x * 256 + threadIdx.x;
    if (t < ACC_CNT) acc[t] = 0.f;
}

__global__ __launch_bounds__(256) void argmax_pa_kernel(
    const float* __restrict__ la, const float* __restrict__ lb,
    const float* __restrict__ pa, int* __restrict__ argA, int* __restrict__ argB,
    float* __restrict__ acc) {
    int i = blockIdx.x * 256 + threadIdx.x;
    float4 a = *(const float4*)&la[(size_t)i * 4];
    float av[4] = {a.x, a.y, a.z, a.w};
    int ba = 0; float bv = av[0];
#pragma unroll
    for (int c = 1; c < 4; ++c) if (av[c] > bv) { bv = av[c]; ba = c; }
    argA[i] = ba;
    float4 b = *(const float4*)&lb[(size_t)i * 4];
    float bw[4] = {b.x, b.y, b.z, b.w};
    int bbi = 0; float bm = bw[0];
#pragma unroll
    for (int c = 1; c < 4; ++c) if (bw[c] > bm) { bm = bw[c]; bbi = c; }
    argB[i] = bbi;
    float p = pa[i];
#pragma unroll
    for (int off = 32; off > 0; off >>= 1) p += __shfl_down(p, off, 64);
    if ((threadIdx.x & 63) == 0) atomicAdd(&acc[ACC_PA], p);
}

// W[256][256] f32 -> Wt[n][k] bf16 (transposed)
__global__ __launch_bounds__(256) void cast_wt_kernel(
    const float* __restrict__ W, unsigned short* __restrict__ Wt) {
    __shared__ float tile[16][17];
    int tx = threadIdx.x & 15, ty = threadIdx.x >> 4;
    int bx = blockIdx.x, by = blockIdx.y;
    tile[ty][tx] = W[(size_t)(by * 16 + ty) * 256 + bx * 16 + tx];
    __syncthreads();
    Wt[(size_t)(bx * 16 + ty) * 256 + by * 16 + tx] = f2bf(tile[tx][ty]);
}

// Fused: Y(bf16) = LN(leaky(X @ W + bias)) * g + be, optional row sq-norms.
template <bool IN_F32>
__global__ __launch_bounds__(256) void gemm_ln_kernel(
    const void* __restrict__ Xv, const unsigned short* __restrict__ Wt,
    const float* __restrict__ bias, const float* __restrict__ gam,
    const float* __restrict__ bet, unsigned short* __restrict__ Y,
    float* __restrict__ norms) {
    __shared__ unsigned short Xs[64 * 40];
    __shared__ unsigned short Ws[256 * 40];
    const int t = threadIdx.x;
    const int L = t & 63, wv = t >> 6;
    const int q = L >> 4, n = L & 15;
    const size_t row0 = (size_t)blockIdx.x * 64;
    f32x4 acc[16];
#pragma unroll
    for (int nt = 0; nt < 16; ++nt) acc[nt] = (f32x4){0.f, 0.f, 0.f, 0.f};

    for (int k0 = 0; k0 < 256; k0 += 32) {
        {
            int r = t >> 2, seg = t & 3;
            if (IN_F32) {
                const float* Xf = (const float*)Xv;
                float4 aa = *(const float4*)&Xf[(row0 + r) * 256 + k0 + seg * 8];
                float4 bb = *(const float4*)&Xf[(row0 + r) * 256 + k0 + seg * 8 + 4];
                uint4 pk;
                pk.x = (unsigned)f2bf(aa.x) | ((unsigned)f2bf(aa.y) << 16);
                pk.y = (unsigned)f2bf(aa.z) | ((unsigned)f2bf(aa.w) << 16);
                pk.z = (unsigned)f2bf(bb.x) | ((unsigned)f2bf(bb.y) << 16);
                pk.w = (unsigned)f2bf(bb.z) | ((unsigned)f2bf(bb.w) << 16);
                *(uint4*)&Xs[r * 40 + seg * 8] = pk;
            } else {
                const unsigned short* Xh = (const unsigned short*)Xv;
                *(uint4*)&Xs[r * 40 + seg * 8] =
                    *(const uint4*)&Xh[(row0 + r) * 256 + k0 + seg * 8];
            }
#pragma unroll
            for (int it = 0; it < 4; ++it) {
                int nn = (t >> 2) + it * 64;
                *(uint4*)&Ws[nn * 40 + seg * 8] =
                    *(const uint4*)&Wt[(size_t)nn * 256 + k0 + seg * 8];
            }
        }
        __syncthreads();
        bf16x8 av = *(const bf16x8*)&Xs[(wv * 16 + n) * 40 + q * 8];
#pragma unroll
        for (int nt = 0; nt < 16; ++nt) {
            bf16x8 bv = *(const bf16x8*)&Ws[(nt * 16 + n) * 40 + q * 8];
            acc[nt] = __builtin_amdgcn_mfma_f32_16x16x32_bf16(av, bv, acc[nt], 0, 0, 0);
        }
        __syncthreads();
    }
    float s[4] = {0.f, 0.f, 0.f, 0.f}, sq[4] = {0.f, 0.f, 0.f, 0.f};
#pragma unroll
    for (int nt = 0; nt < 16; ++nt) {
        float bv = bias[nt * 16 + n];
#pragma unroll
        for (int r = 0; r < 4; ++r) {
            float h = acc[nt][r] + bv;
            h = h >= 0.f ? h : 0.01f * h;
            acc[nt][r] = h;
            s[r] += h; sq[r] += h * h;
        }
    }
#pragma unroll
    for (int r = 0; r < 4; ++r) {
#pragma unroll
        for (int off = 8; off >= 1; off >>= 1) {
            s[r] += __shfl_xor(s[r], off, 64);
            sq[r] += __shfl_xor(sq[r], off, 64);
        }
    }
    float mean[4], inv[4];
#pragma unroll
    for (int r = 0; r < 4; ++r) {
        mean[r] = s[r] * (1.f / 256.f);
        float var = fmaxf(sq[r] * (1.f / 256.f) - mean[r] * mean[r], 0.f);
        inv[r] = rsqrtf(var + 1e-5f);
    }
    float nr[4] = {0.f, 0.f, 0.f, 0.f};
#pragma unroll
    for (int nt = 0; nt < 16; ++nt) {
        float gv = gam[nt * 16 + n], ev = bet[nt * 16 + n];
#pragma unroll
        for (int r = 0; r < 4; ++r) {
            float o = (acc[nt][r] - mean[r]) * inv[r] * gv + ev;
            unsigned short ob = f2bf(o);
            size_t row = row0 + wv * 16 + q * 4 + r;
            Y[row * 256 + nt * 16 + n] = ob;
            float orr = bf2f(ob);
            nr[r] += orr * orr;
        }
    }
    if (norms) {
#pragma unroll
        for (int r = 0; r < 4; ++r) {
#pragma unroll
            for (int off = 8; off >= 1; off >>= 1) nr[r] += __shfl_xor(nr[r], off, 64);
        }
        if (n == 0) {
#pragma unroll
            for (int r = 0; r < 4; ++r)
                norms[row0 + wv * 16 + q * 4 + r] = nr[r];
        }
    }
}

// cdist via MFMA + in/out loss partial + K(bf16) = exp(-2*cost) + K^T(bf16)
// (K^T via padded LDS transpose; feeds the MFMA sinkhorn's v-step A-operand)
__global__ __launch_bounds__(256) void cost_mfma_kernel(
    const unsigned short* __restrict__ E, const float* __restrict__ norms,
    const int* __restrict__ argA, const int* __restrict__ argB,
    const float* __restrict__ pa, const float* __restrict__ pb,
    unsigned short* __restrict__ Kb16, unsigned short* __restrict__ KTb16,
    float* __restrict__ acc) {
    __shared__ unsigned short As[64 * 40];
    __shared__ unsigned short Bs[64 * 40];
    __shared__ unsigned short Ts[64][72];    // [col_local][row_local], 2-way max
    const int t = threadIdx.x;
    const int L = t & 63, wv = t >> 6;
    const int q = L >> 4, n = L & 15;
    const int b = blockIdx.z;
    const int i0 = blockIdx.y * 64, j0 = blockIdx.x * 64;
    const unsigned short* eA = E + (size_t)b * 512 * 256;
    const unsigned short* eB = E + (size_t)(32768 + b * 512) * 256;
    f32x4 dot[4];
#pragma unroll
    for (int nt = 0; nt < 4; ++nt) dot[nt] = (f32x4){0.f, 0.f, 0.f, 0.f};

    for (int k0 = 0; k0 < 256; k0 += 32) {
        int r = t >> 2, seg = t & 3;
        *(uint4*)&As[r * 40 + seg * 8] =
            *(const uint4*)&eA[(size_t)(i0 + r) * 256 + k0 + seg * 8];
        *(uint4*)&Bs[r * 40 + seg * 8] =
            *(const uint4*)&eB[(size_t)(j0 + r) * 256 + k0 + seg * 8];
        __syncthreads();
        bf16x8 av = *(const bf16x8*)&As[(wv * 16 + n) * 40 + q * 8];
#pragma unroll
        for (int nt = 0; nt < 4; ++nt) {
            bf16x8 bv = *(const bf16x8*)&Bs[(nt * 16 + n) * 40 + q * 8];
            dot[nt] = __builtin_amdgcn_mfma_f32_16x16x32_bf16(av, bv, dot[nt], 0, 0, 0);
        }
        __syncthreads();
    }
    int base_row = i0 + wv * 16 + q * 4;
    float nA[4], pA[4]; int cA[4];
#pragma unroll
    for (int r = 0; r < 4; ++r) {
        nA[r] = norms[b * 512 + base_row + r];
        pA[r] = pa[b * 512 + base_row + r];
        cA[r] = argA[b * 512 + base_row + r];
    }
    float part = 0.f;
#pragma unroll
    for (int nt = 0; nt < 4; ++nt) {
        int col = j0 + nt * 16 + n;
        float nB = norms[32768 + b * 512 + col];
        float pB = pb[b * 512 + col];
        int cB = argB[b * 512 + col];
#pragma unroll
        for (int r = 0; r < 4; ++r) {
            float d2 = nA[r] + nB - 2.f * dot[nt][r];
            float c = sqrtf(fmaxf(d2, 0.f));
            float pm = pA[r] * pB;
            float cc = c + (BIGF - BIGF * pm);
            float sgn = (cA[r] == cB) ? 1.f : -1.f;
            part += cc * sgn * pm;
            unsigned short kb = f2bf(expf(-2.f * cc));
            Kb16[((size_t)b * 512 + base_row + r) * 512 + col] = kb;
            Ts[nt * 16 + n][wv * 16 + q * 4 + r] = kb;
        }
    }
    __syncthreads();
    // KT write: thread covers KT row (j0+c), cols i0+seg*16..+15 (coalesced 32B)
    {
        int c = t >> 2, seg = t & 3;
        uint4 p0 = *(const uint4*)&Ts[c][seg * 16];
        uint4 p1 = *(const uint4*)&Ts[c][seg * 16 + 8];
        size_t o = ((size_t)b * 512 + j0 + c) * 512 + i0 + seg * 16;
        *(uint4*)&KTb16[o] = p0;
        *(uint4*)&KTb16[o + 8] = p1;
    }
    float tot = block_reduce_256(part);
    if (threadIdx.x == 0) atomicAdd(&acc[ACC_IN + b], tot);
}

// MFMA Sinkhorn: 1 block (1024 thr, 16 waves) per batch.
// u-step row sums use A=K (row-major); v-step col sums use A=K^T.
// B operand = current vector broadcast to all 16 n-lanes (every column of D
// equals the matvec). 16 k-chunks chained in one accumulator -> complete sums
// with no cross-lane reduction. C layout: row = quad*4+reg (verified m89/m91).
__global__ __launch_bounds__(1024) void sinkhorn_mfma_kernel(
    const unsigned short* __restrict__ K, const unsigned short* __restrict__ KT,
    float* __restrict__ u, float* __restrict__ v) {
    __shared__ unsigned short ubf[512], vbf[512];
    __shared__ float uf[512], vf[512];
    const int b = blockIdx.x;
    const int t = threadIdx.x;
    const int w = t >> 6, L = t & 63;
    const int n = L & 15, quad = L >> 4;
    const float inv512 = 1.f / 512.f;
    const unsigned short* Kb = K + (size_t)b * 262144;
    const unsigned short* KTb = KT + (size_t)b * 262144;
    if (t < 512) { ubf[t] = f2bf(inv512); uf[t] = inv512; }
    __syncthreads();
    for (int it = 0; it < 10; ++it) {
        // ---- v-step: s_j = sum_i KT[j][i] * u_i ; A = KT, vec = ubf
#pragma unroll
        for (int half = 0; half < 2; ++half) {
            int m0 = (w + half * 16) * 16;
            f32x4 acc = (f32x4){0.f, 0.f, 0.f, 0.f};
#pragma unroll
            for (int kc = 0; kc < 16; ++kc) {
                bf16x8 a = *(const bf16x8*)&KTb[(size_t)(m0 + n) * 512 + kc * 32 + quad * 8];
                bf16x8 bv = *(const bf16x8*)&ubf[kc * 32 + quad * 8];
                acc = __builtin_amdgcn_mfma_f32_16x16x32_bf16(a, bv, acc, 0, 0, 0);
            }
            if (n == 0) {
#pragma unroll
                for (int r = 0; r < 4; ++r) {
                    int row = m0 + quad * 4 + r;
                    float val = inv512 / acc[r];
                    vf[row] = val;
                    vbf[row] = f2bf(val);
                }
            }
        }
        __syncthreads();
        // ---- u-step: s_i = sum_j K[i][j] * v_j ; A = K, vec = vbf
#pragma unroll
        for (int half = 0; half < 2; ++half) {
            int m0 = (w + half * 16) * 16;
            f32x4 acc = (f32x4){0.f, 0.f, 0.f, 0.f};
#pragma unroll
            for (int kc = 0; kc < 16; ++kc) {
                bf16x8 a = *(const bf16x8*)&Kb[(size_t)(m0 + n) * 512 + kc * 32 + quad * 8];
                bf16x8 bv = *(const bf16x8*)&vbf[kc * 32 + quad * 8];
                acc = __builtin_amdgcn_mfma_f32_16x16x32_bf16(a, bv, acc, 0, 0, 0);
            }
            if (n == 0) {
#pragma unroll
                for (int r = 0; r < 4; ++r) {
                    int row = m0 + quad * 4 + r;
                    float val = inv512 / acc[r];
                    uf[row] = val;
                    ubf[row] = f2bf(val);
                }
            }
        }
        __syncthreads();
    }
    if (t < 512) {
        u[(size_t)b * 512 + t] = uf[t];
        v[(size_t)b * 512 + t] = vf[t];
    }
}

// sup loss on bf16 K
__global__ __launch_bounds__(256) void sup_kernel(
    const unsigned short* __restrict__ Kb16, const float* __restrict__ u,
    const float* __restrict__ v, const float* __restrict__ rel,
    const float* __restrict__ pa, float* __restrict__ acc) {
    const int nthreads = 4096 * 256;
    int tid = blockIdx.x * 256 + threadIdx.x;
    float part = 0.f;
#pragma unroll
    for (int k = 0; k < 4; ++k) {
        int i4 = tid + k * nthreads;
        int e = i4 * 4;
        int b = e >> 18;
        int i = (e >> 9) & 511;
        int j0 = e & 511;
        ushort4 K4 = *(const ushort4*)&Kb16[(size_t)i4 * 4];
        float4 r4 = *(const float4*)&rel[(size_t)i4 * 4];
        float4 v4 = *(const float4*)&v[b * 512 + j0];
        float ui = u[b * 512 + i] * 512.f;
        float pai = pa[b * 512 + i];
        float d0 = ui * bf2f(K4.x) * v4.x - r4.x;
        float d1 = ui * bf2f(K4.y) * v4.y - r4.y;
        float d2 = ui * bf2f(K4.z) * v4.z - r4.z;
        float d3 = ui * bf2f(K4.w) * v4.w - r4.w;
        part += (d0 * d0 + d1 * d1 + d2 * d2 + d3 * d3) * pai;
    }
    float tot = block_reduce_256(part);
    if (threadIdx.x == 0) atomicAdd(&acc[ACC_SUP + (blockIdx.x & 255)], tot);
}

__global__ __launch_bounds__(256) void final_kernel(const float* __restrict__ acc,
                                                    float* __restrict__ out) {
    int t = threadIdx.x;
    float vin = (t < 64) ? acc[ACC_IN + t] : 0.f;
    float sIn = block_reduce_256(vin);
    float vsup = acc[ACC_SUP + t];
    float sSup = block_reduce_256(vsup);
    if (t == 0)
        out[0] = sIn * (1.f / 16777216.f) + 10.f * sSup / acc[ACC_PA];
}

extern "C" void kernel_launch(void* const* d_in, const int* in_sizes, int n_in,
                              void* d_out, int out_size, void* d_ws, size_t ws_size,
                              hipStream_t stream) {
    const float* la  = (const float*)d_in[0];
    const float* lb  = (const float*)d_in[1];
    const float* xA  = (const float*)d_in[2];
    const float* xB  = (const float*)d_in[3];
    const float* rel = (const float*)d_in[4];
    const float* pa  = (const float*)d_in[5];
    const float* pb  = (const float*)d_in[6];
    const float* W1  = (const float*)d_in[7];
    const float* b1  = (const float*)d_in[8];
    const float* g1  = (const float*)d_in[9];
    const float* be1 = (const float*)d_in[10];
    const float* W2  = (const float*)d_in[11];
    const float* b2  = (const float*)d_in[12];
    const float* g2  = (const float*)d_in[13];
    const float* be2 = (const float*)d_in[14];
    float* out = (float*)d_out;

    float* ws = (float*)d_ws;
    unsigned short* Kb16 = (unsigned short*)(ws + KB_OFF);
    unsigned short* Ebf  = (unsigned short*)(ws + E_OFF);
    unsigned short* Hbf  = (unsigned short*)(ws + H_OFF);   // later KT
    float* norms = ws + NORM_OFF;
    float* u     = ws + U_OFF;
    float* v     = ws + V_OFF;
    int* argA    = (int*)(ws + ARGA_OFF);
    int* argB    = (int*)(ws + ARGB_OFF);
    float* acc   = ws + ACC_OFF;
    unsigned short* Wt1 = (unsigned short*)(ws + WT1_OFF);
    unsigned short* Wt2 = (unsigned short*)(ws + WT2_OFF);
    unsigned short* KTb16 = Hbf;   // Hbf dead after layer-2 gemm

    zero_acc_kernel<<<2, 256, 0, stream>>>(acc);
    argmax_pa_kernel<<<128, 256, 0, stream>>>(la, lb, pa, argA, argB, acc);

    cast_wt_kernel<<<dim3(16, 16), 256, 0, stream>>>(W1, Wt1);
    cast_wt_kernel<<<dim3(16, 16), 256, 0, stream>>>(W2, Wt2);

    // layer 1 (fused cast+gemm+bias+leaky+LN): f32 in, bf16 out
    gemm_ln_kernel<true><<<512, 256, 0, stream>>>(xA, Wt1, b1, g1, be1, Hbf, nullptr);
    gemm_ln_kernel<true><<<512, 256, 0, stream>>>(xB, Wt1, b1, g1, be1,
                                                  Hbf + (size_t)MROWS * DIM, nullptr);
    // layer 2: bf16 in, bf16 out + row norms
    gemm_ln_kernel<false><<<1024, 256, 0, stream>>>(Hbf, Wt2, b2, g2, be2, Ebf, norms);

    // cost + K(bf16) + KT(bf16, overwrites Hbf)
    cost_mfma_kernel<<<dim3(8, 8, 64), 256, 0, stream>>>(Ebf, norms, argA, argB, pa, pb,
                                                         Kb16, KTb16, acc);

    // sinkhorn: MFMA matvecs, 1 block/batch
    sinkhorn_mfma_kernel<<<64, 1024, 0, stream>>>(Kb16, KTb16, u, v);

    sup_kernel<<<4096, 256, 0, stream>>>(Kb16, u, v, rel, pa, acc);
    final_kernel<<<1, 256, 0, stream>>>(acc, out);
}

// Round 8
// 589.914 us; speedup vs baseline: 2.7380x; 1.0063x over previous
//
#include <hip/hip_runtime.h>
#include <math.h>

// Problem constants
#define BSZ 64
#define NPTS 512
#define DIM 256
#define MROWS 32768      // BSZ*NPTS
#define TOTROWS 65536
#define BIGF 1.0e9f

typedef __bf16 bf16x8 __attribute__((ext_vector_type(8)));
typedef float  f32x4  __attribute__((ext_vector_type(4)));

// ws layout (float offsets)
#define KB_OFF    0ull          // K bf16: ushort[16777216]
#define E_OFF     8388608ull    // Ebf: ushort[16777216]
#define H_OFF     16777216ull   // Hbf: ushort[16777216]; reused as KT after layer2
#define NORM_OFF  25165824ull   // 65536 f32
#define U_OFF     25231360ull   // 32768 f32
#define V_OFF     25264128ull   // 32768 f32
#define ARGA_OFF  25296896ull   // 32768 int
#define ARGB_OFF  25329664ull   // 32768 int
#define ACC_OFF   25362432ull   // 512 f32 (321 used)
#define WT1_OFF   25362944ull   // ushort[65536]
#define WT2_OFF   25395712ull   // ushort[65536]

#define ACC_PA   0
#define ACC_IN   1     // 64 slots
#define ACC_SUP  65    // 256 slots
#define ACC_CNT  321

__device__ __forceinline__ float bf2f(unsigned short h) {
    return __uint_as_float(((unsigned int)h) << 16);
}
__device__ __forceinline__ unsigned short f2bf(float f) {
    unsigned int u = __float_as_uint(f);
    u = (u + 0x7FFFu + ((u >> 16) & 1u)) >> 16;
    return (unsigned short)u;
}

// re-entrant
__device__ __forceinline__ float block_reduce_256(float val) {
    __shared__ float sh[4];
    int lane = threadIdx.x & 63;
    int wv = threadIdx.x >> 6;
    __syncthreads();
#pragma unroll
    for (int off = 32; off > 0; off >>= 1) val += __shfl_down(val, off, 64);
    if (lane == 0) sh[wv] = val;
    __syncthreads();
    float r = 0.f;
    if (wv == 0 && lane < 4) r = sh[lane];
    if (wv == 0) {
        r += __shfl_down(r, 2, 64);
        r += __shfl_down(r, 1, 64);
    }
    return r;  // valid in thread 0
}

__global__ void zero_acc_kernel(float* acc) {
    int t = blockIdx.x * 256 + threadIdx.x;
    if (t < ACC_CNT) acc[t] = 0.f;
}

__global__ __launch_bounds__(256) void argmax_pa_kernel(
    const float* __restrict__ la, const float* __restrict__ lb,
    const float* __restrict__ pa, int* __restrict__ argA, int* __restrict__ argB,
    float* __restrict__ acc) {
    int i = blockIdx.x * 256 + threadIdx.x;
    float4 a = *(const float4*)&la[(size_t)i * 4];
    float av[4] = {a.x, a.y, a.z, a.w};
    int ba = 0; float bv = av[0];
#pragma unroll
    for (int c = 1; c < 4; ++c) if (av[c] > bv) { bv = av[c]; ba = c; }
    argA[i] = ba;
    float4 b = *(const float4*)&lb[(size_t)i * 4];
    float bw[4] = {b.x, b.y, b.z, b.w};
    int bbi = 0; float bm = bw[0];
#pragma unroll
    for (int c = 1; c < 4; ++c) if (bw[c] > bm) { bm = bw[c]; bbi = c; }
    argB[i] = bbi;
    float p = pa[i];
#pragma unroll
    for (int off = 32; off > 0; off >>= 1) p += __shfl_down(p, off, 64);
    if ((threadIdx.x & 63) == 0) atomicAdd(&acc[ACC_PA], p);
}

// W[256][256] f32 -> Wt[n][k] bf16 (transposed)
__global__ __launch_bounds__(256) void cast_wt_kernel(
    const float* __restrict__ W, unsigned short* __restrict__ Wt) {
    __shared__ float tile[16][17];
    int tx = threadIdx.x & 15, ty = threadIdx.x >> 4;
    int bx = blockIdx.x, by = blockIdx.y;
    tile[ty][tx] = W[(size_t)(by * 16 + ty) * 256 + bx * 16 + tx];
    __syncthreads();
    Wt[(size_t)(bx * 16 + ty) * 256 + by * 16 + tx] = f2bf(tile[tx][ty]);
}

// Fused: Y(bf16) = LN(leaky(X @ W + bias)) * g + be, optional row sq-norms.
template <bool IN_F32>
__global__ __launch_bounds__(256) void gemm_ln_kernel(
    const void* __restrict__ Xv, const unsigned short* __restrict__ Wt,
    const float* __restrict__ bias, const float* __restrict__ gam,
    const float* __restrict__ bet, unsigned short* __restrict__ Y,
    float* __restrict__ norms) {
    __shared__ unsigned short Xs[64 * 40];
    __shared__ unsigned short Ws[256 * 40];
    const int t = threadIdx.x;
    const int L = t & 63, wv = t >> 6;
    const int q = L >> 4, n = L & 15;
    const size_t row0 = (size_t)blockIdx.x * 64;
    f32x4 acc[16];
#pragma unroll
    for (int nt = 0; nt < 16; ++nt) acc[nt] = (f32x4){0.f, 0.f, 0.f, 0.f};

    for (int k0 = 0; k0 < 256; k0 += 32) {
        {
            int r = t >> 2, seg = t & 3;
            if (IN_F32) {
                const float* Xf = (const float*)Xv;
                float4 aa = *(const float4*)&Xf[(row0 + r) * 256 + k0 + seg * 8];
                float4 bb = *(const float4*)&Xf[(row0 + r) * 256 + k0 + seg * 8 + 4];
                uint4 pk;
                pk.x = (unsigned)f2bf(aa.x) | ((unsigned)f2bf(aa.y) << 16);
                pk.y = (unsigned)f2bf(aa.z) | ((unsigned)f2bf(aa.w) << 16);
                pk.z = (unsigned)f2bf(bb.x) | ((unsigned)f2bf(bb.y) << 16);
                pk.w = (unsigned)f2bf(bb.z) | ((unsigned)f2bf(bb.w) << 16);
                *(uint4*)&Xs[r * 40 + seg * 8] = pk;
            } else {
                const unsigned short* Xh = (const unsigned short*)Xv;
                *(uint4*)&Xs[r * 40 + seg * 8] =
                    *(const uint4*)&Xh[(row0 + r) * 256 + k0 + seg * 8];
            }
#pragma unroll
            for (int it = 0; it < 4; ++it) {
                int nn = (t >> 2) + it * 64;
                *(uint4*)&Ws[nn * 40 + seg * 8] =
                    *(const uint4*)&Wt[(size_t)nn * 256 + k0 + seg * 8];
            }
        }
        __syncthreads();
        bf16x8 av = *(const bf16x8*)&Xs[(wv * 16 + n) * 40 + q * 8];
#pragma unroll
        for (int nt = 0; nt < 16; ++nt) {
            bf16x8 bv = *(const bf16x8*)&Ws[(nt * 16 + n) * 40 + q * 8];
            acc[nt] = __builtin_amdgcn_mfma_f32_16x16x32_bf16(av, bv, acc[nt], 0, 0, 0);
        }
        __syncthreads();
    }
    float s[4] = {0.f, 0.f, 0.f, 0.f}, sq[4] = {0.f, 0.f, 0.f, 0.f};
#pragma unroll
    for (int nt = 0; nt < 16; ++nt) {
        float bv = bias[nt * 16 + n];
#pragma unroll
        for (int r = 0; r < 4; ++r) {
            float h = acc[nt][r] + bv;
            h = h >= 0.f ? h : 0.01f * h;
            acc[nt][r] = h;
            s[r] += h; sq[r] += h * h;
        }
    }
#pragma unroll
    for (int r = 0; r < 4; ++r) {
#pragma unroll
        for (int off = 8; off >= 1; off >>= 1) {
            s[r] += __shfl_xor(s[r], off, 64);
            sq[r] += __shfl_xor(sq[r], off, 64);
        }
    }
    float mean[4], inv[4];
#pragma unroll
    for (int r = 0; r < 4; ++r) {
        mean[r] = s[r] * (1.f / 256.f);
        float var = fmaxf(sq[r] * (1.f / 256.f) - mean[r] * mean[r], 0.f);
        inv[r] = rsqrtf(var + 1e-5f);
    }
    float nr[4] = {0.f, 0.f, 0.f, 0.f};
#pragma unroll
    for (int nt = 0; nt < 16; ++nt) {
        float gv = gam[nt * 16 + n], ev = bet[nt * 16 + n];
#pragma unroll
        for (int r = 0; r < 4; ++r) {
            float o = (acc[nt][r] - mean[r]) * inv[r] * gv + ev;
            unsigned short ob = f2bf(o);
            size_t row = row0 + wv * 16 + q * 4 + r;
            Y[row * 256 + nt * 16 + n] = ob;
            float orr = bf2f(ob);
            nr[r] += orr * orr;
        }
    }
    if (norms) {
#pragma unroll
        for (int r = 0; r < 4; ++r) {
#pragma unroll
            for (int off = 8; off >= 1; off >>= 1) nr[r] += __shfl_xor(nr[r], off, 64);
        }
        if (n == 0) {
#pragma unroll
            for (int r = 0; r < 4; ++r)
                norms[row0 + wv * 16 + q * 4 + r] = nr[r];
        }
    }
}

// cdist via MFMA + in/out loss partial + K(bf16) = exp(-2*cost) + K^T(bf16)
__global__ __launch_bounds__(256) void cost_mfma_kernel(
    const unsigned short* __restrict__ E, const float* __restrict__ norms,
    const int* __restrict__ argA, const int* __restrict__ argB,
    const float* __restrict__ pa, const float* __restrict__ pb,
    unsigned short* __restrict__ Kb16, unsigned short* __restrict__ KTb16,
    float* __restrict__ acc) {
    __shared__ unsigned short As[64 * 40];
    __shared__ unsigned short Bs[64 * 40];
    __shared__ unsigned short Ts[64][72];    // [col_local][row_local], 2-way max
    const int t = threadIdx.x;
    const int L = t & 63, wv = t >> 6;
    const int q = L >> 4, n = L & 15;
    const int b = blockIdx.z;
    const int i0 = blockIdx.y * 64, j0 = blockIdx.x * 64;
    const unsigned short* eA = E + (size_t)b * 512 * 256;
    const unsigned short* eB = E + (size_t)(32768 + b * 512) * 256;
    f32x4 dot[4];
#pragma unroll
    for (int nt = 0; nt < 4; ++nt) dot[nt] = (f32x4){0.f, 0.f, 0.f, 0.f};

    for (int k0 = 0; k0 < 256; k0 += 32) {
        int r = t >> 2, seg = t & 3;
        *(uint4*)&As[r * 40 + seg * 8] =
            *(const uint4*)&eA[(size_t)(i0 + r) * 256 + k0 + seg * 8];
        *(uint4*)&Bs[r * 40 + seg * 8] =
            *(const uint4*)&eB[(size_t)(j0 + r) * 256 + k0 + seg * 8];
        __syncthreads();
        bf16x8 av = *(const bf16x8*)&As[(wv * 16 + n) * 40 + q * 8];
#pragma unroll
        for (int nt = 0; nt < 4; ++nt) {
            bf16x8 bv = *(const bf16x8*)&Bs[(nt * 16 + n) * 40 + q * 8];
            dot[nt] = __builtin_amdgcn_mfma_f32_16x16x32_bf16(av, bv, dot[nt], 0, 0, 0);
        }
        __syncthreads();
    }
    int base_row = i0 + wv * 16 + q * 4;
    float nA[4], pA[4]; int cA[4];
#pragma unroll
    for (int r = 0; r < 4; ++r) {
        nA[r] = norms[b * 512 + base_row + r];
        pA[r] = pa[b * 512 + base_row + r];
        cA[r] = argA[b * 512 + base_row + r];
    }
    float part = 0.f;
#pragma unroll
    for (int nt = 0; nt < 4; ++nt) {
        int col = j0 + nt * 16 + n;
        float nB = norms[32768 + b * 512 + col];
        float pB = pb[b * 512 + col];
        int cB = argB[b * 512 + col];
#pragma unroll
        for (int r = 0; r < 4; ++r) {
            float d2 = nA[r] + nB - 2.f * dot[nt][r];
            float c = sqrtf(fmaxf(d2, 0.f));
            float pm = pA[r] * pB;
            float cc = c + (BIGF - BIGF * pm);
            float sgn = (cA[r] == cB) ? 1.f : -1.f;
            part += cc * sgn * pm;
            unsigned short kb = f2bf(expf(-2.f * cc));
            Kb16[((size_t)b * 512 + base_row + r) * 512 + col] = kb;
            Ts[nt * 16 + n][wv * 16 + q * 4 + r] = kb;
        }
    }
    __syncthreads();
    // KT write: thread covers KT row (j0+c), cols i0+seg*16..+15 (coalesced 32B)
    {
        int c = t >> 2, seg = t & 3;
        uint4 p0 = *(const uint4*)&Ts[c][seg * 16];
        uint4 p1 = *(const uint4*)&Ts[c][seg * 16 + 8];
        size_t o = ((size_t)b * 512 + j0 + c) * 512 + i0 + seg * 16;
        *(uint4*)&KTb16[o] = p0;
        *(uint4*)&KTb16[o + 8] = p1;
    }
    float tot = block_reduce_256(part);
    if (threadIdx.x == 0) atomicAdd(&acc[ACC_IN + b], tot);
}

// MFMA Sinkhorn: 1 block (1024 thr, 16 waves) per batch.
// R7 post-mortem: VGPR cap 64 serialized the 16 A-loads per half-step
// (load->waitcnt->mfma x16 at ~700cyc LLC latency each). Fix:
// __launch_bounds__(1024,4) -> 128-VGPR cap, and all 16 loads hoisted into
// two 8-deep arrays before the MFMA chain; even/odd accumulators break the
// MFMA dependency chain. One (or two) memory latencies per half-step.
__global__ __launch_bounds__(1024, 4) void sinkhorn_mfma_kernel(
    const unsigned short* __restrict__ K, const unsigned short* __restrict__ KT,
    float* __restrict__ u, float* __restrict__ v) {
    __shared__ unsigned short ubf[512], vbf[512];
    __shared__ float uf[512], vf[512];
    const int b = blockIdx.x;
    const int t = threadIdx.x;
    const int w = t >> 6, L = t & 63;
    const int n = L & 15, quad = L >> 4;
    const float inv512 = 1.f / 512.f;
    const unsigned short* Kb = K + (size_t)b * 262144;
    const unsigned short* KTb = KT + (size_t)b * 262144;
    if (t < 512) { ubf[t] = f2bf(inv512); uf[t] = inv512; }
    __syncthreads();
    for (int it = 0; it < 10; ++it) {
        // ---- v-step: s_j = sum_i KT[j][i] * u_i ; A = KT, vec = ubf
#pragma unroll
        for (int half = 0; half < 2; ++half) {
            int m0 = (w + half * 16) * 16;
            const unsigned short* base = &KTb[(size_t)(m0 + n) * 512 + quad * 8];
            bf16x8 a0[8], a1[8];
#pragma unroll
            for (int kc = 0; kc < 8; ++kc) a0[kc] = *(const bf16x8*)(base + kc * 32);
#pragma unroll
            for (int kc = 0; kc < 8; ++kc) a1[kc] = *(const bf16x8*)(base + (kc + 8) * 32);
            f32x4 ae = (f32x4){0.f, 0.f, 0.f, 0.f};
            f32x4 ao = (f32x4){0.f, 0.f, 0.f, 0.f};
#pragma unroll
            for (int kc = 0; kc < 8; ++kc) {
                bf16x8 bv = *(const bf16x8*)&ubf[kc * 32 + quad * 8];
                if (kc & 1) ao = __builtin_amdgcn_mfma_f32_16x16x32_bf16(a0[kc], bv, ao, 0, 0, 0);
                else        ae = __builtin_amdgcn_mfma_f32_16x16x32_bf16(a0[kc], bv, ae, 0, 0, 0);
            }
#pragma unroll
            for (int kc = 0; kc < 8; ++kc) {
                bf16x8 bv = *(const bf16x8*)&ubf[(kc + 8) * 32 + quad * 8];
                if (kc & 1) ao = __builtin_amdgcn_mfma_f32_16x16x32_bf16(a1[kc], bv, ao, 0, 0, 0);
                else        ae = __builtin_amdgcn_mfma_f32_16x16x32_bf16(a1[kc], bv, ae, 0, 0, 0);
            }
            if (n == 0) {
#pragma unroll
                for (int r = 0; r < 4; ++r) {
                    int row = m0 + quad * 4 + r;
                    float val = inv512 / (ae[r] + ao[r]);
                    vf[row] = val;
                    vbf[row] = f2bf(val);
                }
            }
        }
        __syncthreads();
        // ---- u-step: s_i = sum_j K[i][j] * v_j ; A = K, vec = vbf
#pragma unroll
        for (int half = 0; half < 2; ++half) {
            int m0 = (w + half * 16) * 16;
            const unsigned short* base = &Kb[(size_t)(m0 + n) * 512 + quad * 8];
            bf16x8 a0[8], a1[8];
#pragma unroll
            for (int kc = 0; kc < 8; ++kc) a0[kc] = *(const bf16x8*)(base + kc * 32);
#pragma unroll
            for (int kc = 0; kc < 8; ++kc) a1[kc] = *(const bf16x8*)(base + (kc + 8) * 32);
            f32x4 ae = (f32x4){0.f, 0.f, 0.f, 0.f};
            f32x4 ao = (f32x4){0.f, 0.f, 0.f, 0.f};
#pragma unroll
            for (int kc = 0; kc < 8; ++kc) {
                bf16x8 bv = *(const bf16x8*)&vbf[kc * 32 + quad * 8];
                if (kc & 1) ao = __builtin_amdgcn_mfma_f32_16x16x32_bf16(a0[kc], bv, ao, 0, 0, 0);
                else        ae = __builtin_amdgcn_mfma_f32_16x16x32_bf16(a0[kc], bv, ae, 0, 0, 0);
            }
#pragma unroll
            for (int kc = 0; kc < 8; ++kc) {
                bf16x8 bv = *(const bf16x8*)&vbf[(kc + 8) * 32 + quad * 8];
                if (kc & 1) ao = __builtin_amdgcn_mfma_f32_16x16x32_bf16(a1[kc], bv, ao, 0, 0, 0);
                else        ae = __builtin_amdgcn_mfma_f32_16x16x32_bf16(a1[kc], bv, ae, 0, 0, 0);
            }
            if (n == 0) {
#pragma unroll
                for (int r = 0; r < 4; ++r) {
                    int row = m0 + quad * 4 + r;
                    float val = inv512 / (ae[r] + ao[r]);
                    uf[row] = val;
                    ubf[row] = f2bf(val);
                }
            }
        }
        __syncthreads();
    }
    if (t < 512) {
        u[(size_t)b * 512 + t] = uf[t];
        v[(size_t)b * 512 + t] = vf[t];
    }
}

// sup loss on bf16 K
__global__ __launch_bounds__(256) void sup_kernel(
    const unsigned short* __restrict__ Kb16, const float* __restrict__ u,
    const float* __restrict__ v, const float* __restrict__ rel,
    const float* __restrict__ pa, float* __restrict__ acc) {
    const int nthreads = 4096 * 256;
    int tid = blockIdx.x * 256 + threadIdx.x;
    float part = 0.f;
#pragma unroll
    for (int k = 0; k < 4; ++k) {
        int i4 = tid + k * nthreads;
        int e = i4 * 4;
        int b = e >> 18;
        int i = (e >> 9) & 511;
        int j0 = e & 511;
        ushort4 K4 = *(const ushort4*)&Kb16[(size_t)i4 * 4];
        float4 r4 = *(const float4*)&rel[(size_t)i4 * 4];
        float4 v4 = *(const float4*)&v[b * 512 + j0];
        float ui = u[b * 512 + i] * 512.f;
        float pai = pa[b * 512 + i];
        float d0 = ui * bf2f(K4.x) * v4.x - r4.x;
        float d1 = ui * bf2f(K4.y) * v4.y - r4.y;
        float d2 = ui * bf2f(K4.z) * v4.z - r4.z;
        float d3 = ui * bf2f(K4.w) * v4.w - r4.w;
        part += (d0 * d0 + d1 * d1 + d2 * d2 + d3 * d3) * pai;
    }
    float tot = block_reduce_256(part);
    if (threadIdx.x == 0) atomicAdd(&acc[ACC_SUP + (blockIdx.x & 255)], tot);
}

__global__ __launch_bounds__(256) void final_kernel(const float* __restrict__ acc,
                                                    float* __restrict__ out) {
    int t = threadIdx.x;
    float vin = (t < 64) ? acc[ACC_IN + t] : 0.f;
    float sIn = block_reduce_256(vin);
    float vsup = acc[ACC_SUP + t];
    float sSup = block_reduce_256(vsup);
    if (t == 0)
        out[0] = sIn * (1.f / 16777216.f) + 10.f * sSup / acc[ACC_PA];
}

extern "C" void kernel_launch(void* const* d_in, const int* in_sizes, int n_in,
                              void* d_out, int out_size, void* d_ws, size_t ws_size,
                              hipStream_t stream) {
    const float* la  = (const float*)d_in[0];
    const float* lb  = (const float*)d_in[1];
    const float* xA  = (const float*)d_in[2];
    const float* xB  = (const float*)d_in[3];
    const float* rel = (const float*)d_in[4];
    const float* pa  = (const float*)d_in[5];
    const float* pb  = (const float*)d_in[6];
    const float* W1  = (const float*)d_in[7];
    const float* b1  = (const float*)d_in[8];
    const float* g1  = (const float*)d_in[9];
    const float* be1 = (const float*)d_in[10];
    const float* W2  = (const float*)d_in[11];
    const float* b2  = (const float*)d_in[12];
    const float* g2  = (const float*)d_in[13];
    const float* be2 = (const float*)d_in[14];
    float* out = (float*)d_out;

    float* ws = (float*)d_ws;
    unsigned short* Kb16 = (unsigned short*)(ws + KB_OFF);
    unsigned short* Ebf  = (unsigned short*)(ws + E_OFF);
    unsigned short* Hbf  = (unsigned short*)(ws + H_OFF);   // later KT
    float* norms = ws + NORM_OFF;
    float* u     = ws + U_OFF;
    float* v     = ws + V_OFF;
    int* argA    = (int*)(ws + ARGA_OFF);
    int* argB    = (int*)(ws + ARGB_OFF);
    float* acc   = ws + ACC_OFF;
    unsigned short* Wt1 = (unsigned short*)(ws + WT1_OFF);
    unsigned short* Wt2 = (unsigned short*)(ws + WT2_OFF);
    unsigned short* KTb16 = Hbf;   // Hbf dead after layer-2 gemm

    zero_acc_kernel<<<2, 256, 0, stream>>>(acc);
    argmax_pa_kernel<<<128, 256, 0, stream>>>(la, lb, pa, argA, argB, acc);

    cast_wt_kernel<<<dim3(16, 16), 256, 0, stream>>>(W1, Wt1);
    cast_wt_kernel<<<dim3(16, 16), 256, 0, stream>>>(W2, Wt2);

    // layer 1 (fused cast+gemm+bias+leaky+LN): f32 in, bf16 out
    gemm_ln_kernel<true><<<512, 256, 0, stream>>>(xA, Wt1, b1, g1, be1, Hbf, nullptr);
    gemm_ln_kernel<true><<<512, 256, 0, stream>>>(xB, Wt1, b1, g1, be1,
                                                  Hbf + (size_t)MROWS * DIM, nullptr);
    // layer 2: bf16 in, bf16 out + row norms
    gemm_ln_kernel<false><<<1024, 256, 0, stream>>>(Hbf, Wt2, b2, g2, be2, Ebf, norms);

    // cost + K(bf16) + KT(bf16, overwrites Hbf)
    cost_mfma_kernel<<<dim3(8, 8, 64), 256, 0, stream>>>(Ebf, norms, argA, argB, pa, pb,
                                                         Kb16, KTb16, acc);

    // sinkhorn: MFMA matvecs, 1 block/batch
    sinkhorn_mfma_kernel<<<64, 1024, 0, stream>>>(Kb16, KTb16, u, v);

    sup_kernel<<<4096, 256, 0, stream>>>(Kb16, u, v, rel, pa, acc);
    final_kernel<<<1, 256, 0, stream>>>(acc, out);
}